// Round 13
// baseline (302.401 us; speedup 1.0000x reference)
//
#include <hip/hip_runtime.h>

#define N_NODES 4096
#define N_EDGES 524288
#define HID 64

typedef short short8 __attribute__((ext_vector_type(8)));
typedef float f32x4 __attribute__((ext_vector_type(4)));

__device__ __forceinline__ float bcastf(float v, int l) {
    return __int_as_float(__builtin_amdgcn_readlane(__float_as_int(v), l));
}

__device__ __forceinline__ void wave_sum2(float& a, float& b) {
    #pragma unroll
    for (int off = 32; off > 0; off >>= 1) {
        a += __shfl_xor(a, off, 64);
        b += __shfl_xor(b, off, 64);
    }
}

__device__ __forceinline__ short f2bf(float f) {         // RNE
    unsigned u = __float_as_uint(f);
    u = u + 0x7FFFu + ((u >> 16) & 1u);
    return (short)(u >> 16);
}
__device__ __forceinline__ float bf2f(short s) {
    return __uint_as_float(((unsigned)(unsigned short)s) << 16);
}
__device__ __forceinline__ void split_cheap(float f, short& hi, short& lo) {
    unsigned u = __float_as_uint(f);
    unsigned hb = u & 0xffff0000u;
    float lof = f - __uint_as_float(hb);
    hi = (short)(u >> 16);
    lo = (short)(__float_as_uint(lof) >> 16);
}

// ------- fused: xe hi/lo planes + dst histogram with rank + weight prepack -------
__global__ void xe_hist_wprep(const float* __restrict__ x, const float* __restrict__ emb,
                              const int* __restrict__ etype, const int* __restrict__ ei,
                              const float* __restrict__ w1, const float* __restrict__ w2,
                              unsigned short* __restrict__ xh, unsigned short* __restrict__ xl,
                              int* __restrict__ cnt, int* __restrict__ rank,
                              unsigned short* __restrict__ w1fh, unsigned short* __restrict__ w1fl,
                              unsigned short* __restrict__ w2fh, unsigned short* __restrict__ w2fl) {
    int tid = blockIdx.x * 256 + threadIdx.x;    // grid exactly E
    int d = ei[N_EDGES + tid];
    rank[tid] = atomicAdd(&cnt[d], 1);
    if (tid < N_NODES * 16) {
        int n = tid >> 4, i = tid & 15;
        float v = 0.f;
        if (i < 6) v = x[n * 6 + i];
        else if (i < 14) v = emb[etype[n] * 8 + (i - 6)];
        short hi = f2bf(v);
        short lo = f2bf(v - bf2f(hi));
        xh[tid] = (unsigned short)hi;
        xl[tid] = (unsigned short)lo;
    }
    if (tid < 2048) {
        int g = tid >> 9, ln = (tid >> 3) & 63, j = tid & 7;
        int mm = ln & 15, qq = ln >> 4;
        int k = qq * 8 + j;
        float w = (k < 15) ? w1[(g * 16 + mm) * 15 + k] : 0.f;
        short hi = f2bf(w);
        w1fh[tid] = (unsigned short)hi;
        w1fl[tid] = (unsigned short)f2bf(w - bf2f(hi));
    }
    if (tid < 4096) {
        int idx = tid >> 9, ln = (tid >> 3) & 63, j = tid & 7;
        int mm = ln & 15, qq = ln >> 4;
        int g = idx >> 1, tt = idx & 1;
        float w = w2[(g * 16 + mm) * 64 + tt * 32 + qq * 8 + j];
        short hi = f2bf(w);
        w2fh[tid] = (unsigned short)hi;
        w2fl[tid] = (unsigned short)f2bf(w - bf2f(hi));
    }
}

// ---------------- exclusive scan over 4096 counters (256 threads) ----------------
__global__ void scan_kernel(const int* __restrict__ cnt, int* __restrict__ bnd) {
    __shared__ int wsum[4];
    int t = threadIdx.x;
    int base = t * 16;
    int T = 0;
    #pragma unroll
    for (int j = 0; j < 16; j++) T += cnt[base + j];
    int inc = T;
    int l = t & 63;
    #pragma unroll
    for (int off = 1; off < 64; off <<= 1) {
        int v = __shfl_up(inc, off, 64);
        if (l >= off) inc += v;
    }
    int wv = t >> 6;
    if (l == 63) wsum[wv] = inc;
    __syncthreads();
    int wo = 0;
    for (int w = 0; w < wv; w++) wo += wsum[w];
    int run = wo + inc - T;
    #pragma unroll
    for (int j = 0; j < 16; j++) {
        bnd[base + j] = run;
        run += cnt[base + j];
    }
    if (t == 255) bnd[4096] = run;
}

// ---------------- scatter into sorted order (atomic-free) ----------------
__global__ void scatter_kernel(const int* __restrict__ ei, const float* __restrict__ edge_attr,
                               const int* __restrict__ bnd, const int* __restrict__ rank,
                               int* __restrict__ ssrc, float* __restrict__ sea) {
    int e = blockIdx.x * 256 + threadIdx.x;
    int d = ei[N_EDGES + e];
    int pos = bnd[d] + rank[e];
    ssrc[pos] = ei[e];
    sea[pos] = edge_attr[e];
}

// ------- edge MLP via MFMA: block = node, wave = quarter (stride-4 tiles) -------
__global__ void __launch_bounds__(256) edge_gather_mfma(
        const unsigned short* __restrict__ xh, const unsigned short* __restrict__ xl,
        const int* __restrict__ ssrc, const float* __restrict__ sea,
        const int* __restrict__ bnd,
        const unsigned short* __restrict__ w1fh, const unsigned short* __restrict__ w1fl,
        const unsigned short* __restrict__ w2fh, const unsigned short* __restrict__ w2fl,
        const float* __restrict__ w1, const float* __restrict__ b1,
        const float* __restrict__ b2,
        const float* __restrict__ lg, const float* __restrict__ lb,
        float* __restrict__ h) {
    __shared__ float Y[4][16 * 68];
    __shared__ float hpart[4][64];
    int lane = threadIdx.x & 63;
    int wv = threadIdx.x >> 6;
    int m = lane & 15;
    int q = lane >> 4;
    float* Yw = Y[wv];

    short8 b1h[4], b1l[4], b2h[8], b2l[8];
    #pragma unroll
    for (int g = 0; g < 4; g++) {
        b1h[g] = *(const short8*)(w1fh + (g * 64 + lane) * 8);
        b1l[g] = *(const short8*)(w1fl + (g * 64 + lane) * 8);
    }
    #pragma unroll
    for (int idx = 0; idx < 8; idx++) {
        b2h[idx] = *(const short8*)(w2fh + (idx * 64 + lane) * 8);
        b2l[idx] = *(const short8*)(w2fl + (idx * 64 + lane) * 8);
    }
    float w14[4], b1v[4], b2v[4], gam[4], bet[4];
    #pragma unroll
    for (int g = 0; g < 4; g++) {
        int row = g * 16 + m;
        w14[g] = w1[row * 15 + 14];
        b1v[g] = b1[row];
        b2v[g] = b2[row];
        gam[g] = lg[row];
        bet[g] = lb[row];
    }

    int node = blockIdx.x;
    int start = bnd[node], end = bnd[node + 1];
    int ntiles = (end - start + 15) >> 4;
    float acc[4] = {0.f, 0.f, 0.f, 0.f};

    for (int t = wv; t < ntiles; t += 4) {
        int base = start + t * 16;
        int e = base + m;
        int srcn = ssrc[(e < end) ? e : (end - 1)];
        short8 a1h = (short8)0, a1l = (short8)0;
        if (q < 2) {
            a1h = *(const short8*)(xh + srcn * 16 + q * 8);
            a1l = *(const short8*)(xl + srcn * 16 + q * 8);
        }
        float ea[4];
        #pragma unroll
        for (int i = 0; i < 4; i++) {
            int idx = base + q * 4 + i;
            ea[i] = (idx < end) ? sea[idx] : 0.f;
        }
        f32x4 c1[4];
        #pragma unroll
        for (int g = 0; g < 4; g++) {
            f32x4 c = {0.f, 0.f, 0.f, 0.f};
            c = __builtin_amdgcn_mfma_f32_16x16x32_bf16(a1l, b1h[g], c, 0, 0, 0);
            c = __builtin_amdgcn_mfma_f32_16x16x32_bf16(a1h, b1l[g], c, 0, 0, 0);
            c = __builtin_amdgcn_mfma_f32_16x16x32_bf16(a1h, b1h[g], c, 0, 0, 0);
            c1[g] = c;
        }
        float s[4] = {0, 0, 0, 0}, s2[4] = {0, 0, 0, 0};
        float t1[4][4];
        #pragma unroll
        for (int g = 0; g < 4; g++) {
            #pragma unroll
            for (int i = 0; i < 4; i++) {
                float v = c1[g][i] + b1v[g] + w14[g] * ea[i];
                v = fmaxf(v, 0.f);
                t1[g][i] = v;
                s[i] += v;
                s2[i] += v * v;
            }
        }
        #pragma unroll
        for (int off = 1; off < 16; off <<= 1) {
            #pragma unroll
            for (int i = 0; i < 4; i++) {
                s[i] += __shfl_xor(s[i], off, 64);
                s2[i] += __shfl_xor(s2[i], off, 64);
            }
        }
        #pragma unroll
        for (int i = 0; i < 4; i++) {
            float mean = s[i] * (1.f / 64.f);
            float var = s2[i] * (1.f / 64.f) - mean * mean;
            s[i] = mean;
            s2[i] = rsqrtf(var + 1e-5f);
        }
        #pragma unroll
        for (int g = 0; g < 4; g++) {
            #pragma unroll
            for (int i = 0; i < 4; i++) {
                float y = (t1[g][i] - s[i]) * s2[i] * gam[g] + bet[g];
                Yw[(q * 4 + i) * 68 + g * 16 + m] = y;
            }
        }
        short8 a2h[2], a2l[2];
        #pragma unroll
        for (int t2 = 0; t2 < 2; t2++) {
            #pragma unroll
            for (int j = 0; j < 8; j++) {
                float v = Yw[m * 68 + t2 * 32 + q * 8 + j];
                short hi, lo;
                split_cheap(v, hi, lo);
                a2h[t2][j] = hi;
                a2l[t2][j] = lo;
            }
        }
        float s_[4] = {0, 0, 0, 0}, s2_[4] = {0, 0, 0, 0};
        float t2v[4][4];
        #pragma unroll
        for (int g = 0; g < 4; g++) {
            f32x4 c = {0.f, 0.f, 0.f, 0.f};
            #pragma unroll
            for (int t2 = 0; t2 < 2; t2++) {
                c = __builtin_amdgcn_mfma_f32_16x16x32_bf16(a2l[t2], b2h[g * 2 + t2], c, 0, 0, 0);
                c = __builtin_amdgcn_mfma_f32_16x16x32_bf16(a2h[t2], b2l[g * 2 + t2], c, 0, 0, 0);
                c = __builtin_amdgcn_mfma_f32_16x16x32_bf16(a2h[t2], b2h[g * 2 + t2], c, 0, 0, 0);
            }
            #pragma unroll
            for (int i = 0; i < 4; i++) {
                float v = c[i] + b2v[g];
                v = fmaxf(v, 0.f);
                t2v[g][i] = v;
                s_[i] += v;
                s2_[i] += v * v;
            }
        }
        #pragma unroll
        for (int off = 1; off < 16; off <<= 1) {
            #pragma unroll
            for (int i = 0; i < 4; i++) {
                s_[i] += __shfl_xor(s_[i], off, 64);
                s2_[i] += __shfl_xor(s2_[i], off, 64);
            }
        }
        #pragma unroll
        for (int i = 0; i < 4; i++) {
            float mean = s_[i] * (1.f / 64.f);
            float var = s2_[i] * (1.f / 64.f) - mean * mean;
            float rs = rsqrtf(var + 1e-5f);
            bool valid = (base + q * 4 + i) < end;
            #pragma unroll
            for (int g = 0; g < 4; g++) {
                float z = (t2v[g][i] - mean) * rs * gam[g] + bet[g];
                if (valid) acc[g] += z;
            }
        }
    }
    #pragma unroll
    for (int g = 0; g < 4; g++) {
        acc[g] += __shfl_xor(acc[g], 16, 64);
        acc[g] += __shfl_xor(acc[g], 32, 64);
    }
    float a01 = (q & 1) ? acc[1] : acc[0];
    float a23 = (q & 1) ? acc[3] : acc[2];
    float av = (q & 2) ? a23 : a01;
    hpart[wv][q * 16 + m] = av;
    __syncthreads();
    if (threadIdx.x < 64) {
        int f = threadIdx.x;
        h[node * 64 + f] = (hpart[0][f] + hpart[1][f]) + (hpart[2][f] + hpart[3][f]);
    }
}

// ---------------- qkv projection -> bf16 planes (q,k hi/lo; vT single) ----------------
__global__ void qkv_kernel(const float* __restrict__ h, const float* __restrict__ w,
                           const float* __restrict__ b,
                           unsigned short* __restrict__ qhp, unsigned short* __restrict__ qlp,
                           unsigned short* __restrict__ khp, unsigned short* __restrict__ klp,
                           unsigned short* __restrict__ vT) {
    __shared__ float wl[192 * 65];
    __shared__ unsigned short vs[256];
    for (int i = threadIdx.x; i < 192 * 64; i += blockDim.x) {
        int r = i >> 6, c = i & 63;
        wl[r * 65 + c] = w[i];
    }
    __syncthreads();
    int lane = threadIdx.x & 63;
    int wv = threadIdx.x >> 6;
    int n = blockIdx.x * 4 + wv;
    int j = lane;
    float hj = h[n * 64 + j];
    float aq = b[j], ak = b[j + 64], av = b[j + 128];
    #pragma unroll
    for (int k = 0; k < 64; k++) {
        float hk = bcastf(hj, k);
        aq = fmaf(wl[j * 65 + k], hk, aq);
        ak = fmaf(wl[(j + 64) * 65 + k], hk, ak);
        av = fmaf(wl[(j + 128) * 65 + k], hk, av);
    }
    aq *= 0.25f * 1.44269504f;   // 1/sqrt(16) * log2(e): softmax in base-2 domain
    int head = j >> 4, d = j & 15;
    size_t idx = ((size_t)(head * N_NODES + n)) * 16 + d;
    short qhi = f2bf(aq);
    qhp[idx] = (unsigned short)qhi;
    qlp[idx] = (unsigned short)f2bf(aq - bf2f(qhi));
    short khi = f2bf(ak);
    khp[idx] = (unsigned short)khi;
    klp[idx] = (unsigned short)f2bf(ak - bf2f(khi));
    vs[threadIdx.x] = (unsigned short)f2bf(av);   // vs[node_in_block*64 + feat]
    __syncthreads();
    int t = threadIdx.x;
    int f = t >> 2, c = t & 3;
    vT[(size_t)f * N_NODES + blockIdx.x * 4 + c] = vs[c * 64 + f];
}

// ------- attention via MFMA: wave = (head, 16-q tile, 512-key chunk), 8192 tasks -------
__global__ void __launch_bounds__(256) attn_mfma(
        const unsigned short* __restrict__ qhp, const unsigned short* __restrict__ qlp,
        const unsigned short* __restrict__ khp, const unsigned short* __restrict__ klp,
        const unsigned short* __restrict__ vT,
        float* __restrict__ part_o, float* __restrict__ part_ml) {
    __shared__ unsigned short Pl[4][16 * 72];
    int lane = threadIdx.x & 63;
    int wv = threadIdx.x >> 6;
    int m = lane & 15;
    int g = lane >> 4;
    unsigned short* Pw = Pl[wv];
    const short8 vones = {0x3F80, 0x3F80, 0x3F80, 0x3F80, 0x3F80, 0x3F80, 0x3F80, 0x3F80};

    int wid = blockIdx.x * 4 + wv;     // 0..8191
    int kc = wid & 7;                  // 8 chunks of 512 keys
    int qt = (wid >> 3) & 255;
    int head = wid >> 11;

    short8 aqh = (short8)0, aql = (short8)0;
    if (g < 2) {
        size_t qi = ((size_t)(head * N_NODES + qt * 16 + m)) * 16 + g * 8;
        aqh = *(const short8*)(qhp + qi);
        aql = *(const short8*)(qlp + qi);
    }
    float mS[4], lS[4];
    #pragma unroll
    for (int r = 0; r < 4; r++) { mS[r] = -3e38f; lS[r] = 0.f; }
    f32x4 Ot = {0.f, 0.f, 0.f, 0.f};

    const unsigned short* khb = khp + (size_t)head * N_NODES * 16;
    const unsigned short* klb = klp + (size_t)head * N_NODES * 16;
    const unsigned short* vtb = vT + (size_t)(head * 16 + m) * N_NODES;

    for (int bblk = 0; bblk < 8; bblk++) {
        int n0 = kc * 512 + bblk * 64;
        f32x4 S[4];
        #pragma unroll
        for (int s = 0; s < 4; s++) {
            short8 bkh = (short8)0, bkl = (short8)0;
            if (g < 2) {
                size_t ki = ((size_t)(n0 + s * 16 + m)) * 16 + g * 8;
                bkh = *(const short8*)(khb + ki);
                bkl = *(const short8*)(klb + ki);
            }
            f32x4 c = {0.f, 0.f, 0.f, 0.f};
            c = __builtin_amdgcn_mfma_f32_16x16x32_bf16(aqh, bkl, c, 0, 0, 0);
            c = __builtin_amdgcn_mfma_f32_16x16x32_bf16(aql, bkh, c, 0, 0, 0);
            c = __builtin_amdgcn_mfma_f32_16x16x32_bf16(aqh, bkh, c, 0, 0, 0);
            S[s] = c;
        }
        float mr[4];
        #pragma unroll
        for (int r = 0; r < 4; r++)
            mr[r] = fmaxf(fmaxf(S[0][r], S[1][r]), fmaxf(S[2][r], S[3][r]));
        #pragma unroll
        for (int off = 1; off < 16; off <<= 1)
            #pragma unroll
            for (int r = 0; r < 4; r++) mr[r] = fmaxf(mr[r], __shfl_xor(mr[r], off, 64));
        float alpha[4];
        #pragma unroll
        for (int r = 0; r < 4; r++) {
            float mn = fmaxf(mS[r], mr[r]);
            alpha[r] = exp2f(mS[r] - mn);
            mS[r] = mn;
        }
        #pragma unroll
        for (int s = 0; s < 4; s++) {
            #pragma unroll
            for (int r = 0; r < 4; r++) {
                float p = exp2f(S[s][r] - mS[r]);
                Pw[(g * 4 + r) * 72 + s * 16 + m] = (unsigned short)f2bf(p);
            }
        }
        #pragma unroll
        for (int r = 0; r < 4; r++) lS[r] *= alpha[r];
        int sel = lane & 3;
        float a01 = (sel & 1) ? alpha[1] : alpha[0];
        float a23 = (sel & 1) ? alpha[3] : alpha[2];
        float aown = (sel & 2) ? a23 : a01;
        int srcl = ((m >> 2) << 4) | (m & 3);
        float ab = __int_as_float(__builtin_amdgcn_ds_bpermute(srcl << 2, __float_as_int(aown)));
        #pragma unroll
        for (int r = 0; r < 4; r++) Ot[r] *= ab;
        // PV + row-sums via ones-MFMA (cl[*] = rowsum[q=m]); bpermute to S-layout
        f32x4 cl = {0.f, 0.f, 0.f, 0.f};
        #pragma unroll
        for (int t = 0; t < 2; t++) {
            short8 avf = *(const short8*)(vtb + n0 + t * 32 + g * 8);
            short8 bpf = *(const short8*)(Pw + m * 72 + t * 32 + g * 8);
            cl = __builtin_amdgcn_mfma_f32_16x16x32_bf16(vones, bpf, cl, 0, 0, 0);
            Ot = __builtin_amdgcn_mfma_f32_16x16x32_bf16(avf, bpf, Ot, 0, 0, 0);
        }
        #pragma unroll
        for (int r = 0; r < 4; r++) {
            float rsum = __int_as_float(
                __builtin_amdgcn_ds_bpermute((g * 4 + r) << 2, __float_as_int(cl[0])));
            lS[r] += rsum;
        }
    }
    size_t pb = ((size_t)(head * 8 + kc) * 256 + qt) * 256;
    *(f32x4*)(part_o + pb + m * 16 + g * 4) = Ot;
    if (m == 0) {
        size_t mb = ((size_t)(head * 8 + kc) * 256 + qt) * 32;
        #pragma unroll
        for (int r = 0; r < 4; r++) {
            part_ml[mb + g * 4 + r] = mS[r];
            part_ml[mb + 16 + g * 4 + r] = lS[r];
        }
    }
}

// ---------------- fused merge (8 chunks) + out_proj + residual + LN + final ----------------
__global__ void post_kernel(const float* __restrict__ h,
                            const float* __restrict__ part_o, const float* __restrict__ part_ml,
                            const float* __restrict__ opw, const float* __restrict__ opb,
                            const float* __restrict__ ag, const float* __restrict__ ab,
                            const float* __restrict__ ow, const float* __restrict__ ob,
                            float* __restrict__ out) {
    __shared__ float wl1[64 * 65];
    __shared__ float wl2[64 * 65];
    for (int i = threadIdx.x; i < 4096; i += blockDim.x) {
        int r = i >> 6, c = i & 63;
        wl1[r * 65 + c] = opw[i];
        wl2[r * 65 + c] = ow[i];
    }
    __syncthreads();
    int lane = threadIdx.x & 63;
    int n = blockIdx.x * 4 + (threadIdx.x >> 6);
    int j = lane;
    int head = j >> 4, d = j & 15;
    int qt = n >> 4, qi = n & 15;
    float M = -3e38f, L = 0.f, Ov = 0.f;
    #pragma unroll
    for (int c = 0; c < 8; c++) {
        size_t base = ((size_t)(head * 8 + c) * 256 + qt);
        float mc = part_ml[base * 32 + qi];
        float lc = part_ml[base * 32 + 16 + qi];
        float ov = part_o[base * 256 + qi * 16 + d];
        if (mc > M) {
            float sc = exp2f(M - mc);
            M = mc;
            L = L * sc + lc;
            Ov = Ov * sc + ov;
        } else {
            float sc = exp2f(mc - M);
            L = fmaf(lc, sc, L);
            Ov = fmaf(ov, sc, Ov);
        }
    }
    float oj = Ov / L;
    float acc = opb[j];
    #pragma unroll
    for (int k = 0; k < 64; k++) acc = fmaf(wl1[j * 65 + k], bcastf(oj, k), acc);
    float r = h[n * 64 + j] + acc;
    float s = r, s2 = r * r;
    wave_sum2(s, s2);
    float mean = s * (1.f / 64.f);
    float var = s2 * (1.f / 64.f) - mean * mean;
    float hn = (r - mean) * rsqrtf(var + 1e-5f) * ag[j] + ab[j];
    float acc2 = ob[j];
    #pragma unroll
    for (int k = 0; k < 64; k++) acc2 = fmaf(wl2[j * 65 + k], bcastf(hn, k), acc2);
    out[n * 64 + j] = acc2;
}

extern "C" void kernel_launch(void* const* d_in, const int* in_sizes, int n_in,
                              void* d_out, int out_size, void* d_ws, size_t ws_size,
                              hipStream_t stream) {
    const float* x        = (const float*)d_in[0];
    const float* edge_attr= (const float*)d_in[1];
    const float* emb      = (const float*)d_in[2];
    const float* lin1_w   = (const float*)d_in[3];
    const float* lin1_b   = (const float*)d_in[4];
    const float* lay_w    = (const float*)d_in[5];
    const float* lay_b    = (const float*)d_in[6];
    const float* ln_g     = (const float*)d_in[7];
    const float* ln_b     = (const float*)d_in[8];
    const float* ipw      = (const float*)d_in[9];
    const float* ipb      = (const float*)d_in[10];
    const float* opw      = (const float*)d_in[11];
    const float* opb      = (const float*)d_in[12];
    const float* ang      = (const float*)d_in[13];
    const float* anb      = (const float*)d_in[14];
    const float* ow       = (const float*)d_in[15];
    const float* ob       = (const float*)d_in[16];
    const int*   ei       = (const int*)d_in[17];
    const int*   et       = (const int*)d_in[18];

    char* wsb = (char*)d_ws;
    size_t off = 0;
    unsigned short* xe_hi = (unsigned short*)(wsb + off); off += 131072;
    unsigned short* xe_lo = (unsigned short*)(wsb + off); off += 131072;
    float* h              = (float*)(wsb + off);          off += 1048576;
    unsigned short* qhp   = (unsigned short*)(wsb + off); off += 524288;
    unsigned short* qlp   = (unsigned short*)(wsb + off); off += 524288;
    unsigned short* khp   = (unsigned short*)(wsb + off); off += 524288;
    unsigned short* klp   = (unsigned short*)(wsb + off); off += 524288;
    unsigned short* vT    = (unsigned short*)(wsb + off); off += 524288;
    float* part_o         = (float*)(wsb + off);          off += 8388608;
    float* part_ml        = (float*)(wsb + off);          off += 1048576;
    int*   cnt            = (int*)(wsb + off);            off += 16384;
    int*   bnd            = (int*)(wsb + off);            off += 16388;
    off = (off + 255) & ~(size_t)255;
    int*   rank           = (int*)(wsb + off);            off += 2097152;
    int*   ssrc           = (int*)(wsb + off);            off += 2097152;
    float* sea            = (float*)(wsb + off);          off += 2097152;
    unsigned short* w1fh  = (unsigned short*)(wsb + off); off += 4096;
    unsigned short* w1fl  = (unsigned short*)(wsb + off); off += 4096;
    unsigned short* w2fh  = (unsigned short*)(wsb + off); off += 8192;
    unsigned short* w2fl  = (unsigned short*)(wsb + off); off += 8192;

    (void)hipMemsetAsync(cnt, 0, 4096 * sizeof(int), stream);
    xe_hist_wprep<<<2048, 256, 0, stream>>>(x, emb, et, ei, lin1_w, lay_w,
                                            xe_hi, xe_lo, cnt, rank,
                                            w1fh, w1fl, w2fh, w2fl);
    scan_kernel<<<1, 256, 0, stream>>>(cnt, bnd);
    scatter_kernel<<<2048, 256, 0, stream>>>(ei, edge_attr, bnd, rank, ssrc, sea);
    edge_gather_mfma<<<4096, 256, 0, stream>>>(xe_hi, xe_lo, ssrc, sea, bnd,
                                               w1fh, w1fl, w2fh, w2fl,
                                               lin1_w, lin1_b, lay_b, ln_g, ln_b, h);
    qkv_kernel<<<1024, 256, 0, stream>>>(h, ipw, ipb, qhp, qlp, khp, klp, vT);
    attn_mfma<<<2048, 256, 0, stream>>>(qhp, qlp, khp, klp, vT, part_o, part_ml);
    post_kernel<<<1024, 256, 0, stream>>>(h, part_o, part_ml, opw, opb, ang, anb, ow, ob,
                                          (float*)d_out);
}

// Round 14
// 271.383 us; speedup vs baseline: 1.1143x; 1.1143x over previous
//
#include <hip/hip_runtime.h>

#define N_NODES 4096
#define N_EDGES 524288
#define HID 64

typedef short short8 __attribute__((ext_vector_type(8)));
typedef float f32x4 __attribute__((ext_vector_type(4)));

__device__ __forceinline__ float bcastf(float v, int l) {
    return __int_as_float(__builtin_amdgcn_readlane(__float_as_int(v), l));
}

__device__ __forceinline__ void wave_sum2(float& a, float& b) {
    #pragma unroll
    for (int off = 32; off > 0; off >>= 1) {
        a += __shfl_xor(a, off, 64);
        b += __shfl_xor(b, off, 64);
    }
}

__device__ __forceinline__ short f2bf(float f) {         // RNE
    unsigned u = __float_as_uint(f);
    u = u + 0x7FFFu + ((u >> 16) & 1u);
    return (short)(u >> 16);
}
__device__ __forceinline__ float bf2f(short s) {
    return __uint_as_float(((unsigned)(unsigned short)s) << 16);
}
__device__ __forceinline__ void split_cheap(float f, short& hi, short& lo) {
    unsigned u = __float_as_uint(f);
    unsigned hb = u & 0xffff0000u;
    float lof = f - __uint_as_float(hb);
    hi = (short)(u >> 16);
    lo = (short)(__float_as_uint(lof) >> 16);
}

// --- fused: xe hi/lo planes + dst histogram with rank + weight prepack (w1,w2,ipw) ---
__global__ void xe_hist_wprep(const float* __restrict__ x, const float* __restrict__ emb,
                              const int* __restrict__ etype, const int* __restrict__ ei,
                              const float* __restrict__ w1, const float* __restrict__ w2,
                              const float* __restrict__ ipw,
                              unsigned short* __restrict__ xh, unsigned short* __restrict__ xl,
                              int* __restrict__ cnt, int* __restrict__ rank,
                              unsigned short* __restrict__ w1fh, unsigned short* __restrict__ w1fl,
                              unsigned short* __restrict__ w2fh, unsigned short* __restrict__ w2fl,
                              unsigned short* __restrict__ ipfh, unsigned short* __restrict__ ipfl) {
    int tid = blockIdx.x * 256 + threadIdx.x;    // grid exactly E
    int d = ei[N_EDGES + tid];
    rank[tid] = atomicAdd(&cnt[d], 1);
    if (tid < N_NODES * 16) {
        int n = tid >> 4, i = tid & 15;
        float v = 0.f;
        if (i < 6) v = x[n * 6 + i];
        else if (i < 14) v = emb[etype[n] * 8 + (i - 6)];
        short hi = f2bf(v);
        short lo = f2bf(v - bf2f(hi));
        xh[tid] = (unsigned short)hi;
        xl[tid] = (unsigned short)lo;
    }
    if (tid < 2048) {
        int g = tid >> 9, ln = (tid >> 3) & 63, j = tid & 7;
        int mm = ln & 15, qq = ln >> 4;
        int k = qq * 8 + j;
        float w = (k < 15) ? w1[(g * 16 + mm) * 15 + k] : 0.f;
        short hi = f2bf(w);
        w1fh[tid] = (unsigned short)hi;
        w1fl[tid] = (unsigned short)f2bf(w - bf2f(hi));
    }
    if (tid < 4096) {
        int idx = tid >> 9, ln = (tid >> 3) & 63, j = tid & 7;
        int mm = ln & 15, qq = ln >> 4;
        int g = idx >> 1, tt = idx & 1;
        float w = w2[(g * 16 + mm) * 64 + tt * 32 + qq * 8 + j];
        short hi = f2bf(w);
        w2fh[tid] = (unsigned short)hi;
        w2fl[tid] = (unsigned short)f2bf(w - bf2f(hi));
    }
    if (tid < 12288) {
        int idx = tid >> 9, ln = (tid >> 3) & 63, j = tid & 7;
        int mm = ln & 15, qq = ln >> 4;
        int og = idx >> 1, tt = idx & 1;
        float w = ipw[(og * 16 + mm) * 64 + tt * 32 + qq * 8 + j];
        short hi = f2bf(w);
        ipfh[tid] = (unsigned short)hi;
        ipfl[tid] = (unsigned short)f2bf(w - bf2f(hi));
    }
}

// ---------------- exclusive scan over 4096 counters (256 threads) ----------------
__global__ void scan_kernel(const int* __restrict__ cnt, int* __restrict__ bnd) {
    __shared__ int wsum[4];
    int t = threadIdx.x;
    int base = t * 16;
    int T = 0;
    #pragma unroll
    for (int j = 0; j < 16; j++) T += cnt[base + j];
    int inc = T;
    int l = t & 63;
    #pragma unroll
    for (int off = 1; off < 64; off <<= 1) {
        int v = __shfl_up(inc, off, 64);
        if (l >= off) inc += v;
    }
    int wv = t >> 6;
    if (l == 63) wsum[wv] = inc;
    __syncthreads();
    int wo = 0;
    for (int w = 0; w < wv; w++) wo += wsum[w];
    int run = wo + inc - T;
    #pragma unroll
    for (int j = 0; j < 16; j++) {
        bnd[base + j] = run;
        run += cnt[base + j];
    }
    if (t == 255) bnd[4096] = run;
}

// ---------------- scatter into sorted order (atomic-free) ----------------
__global__ void scatter_kernel(const int* __restrict__ ei, const float* __restrict__ edge_attr,
                               const int* __restrict__ bnd, const int* __restrict__ rank,
                               int* __restrict__ ssrc, float* __restrict__ sea) {
    int e = blockIdx.x * 256 + threadIdx.x;
    int d = ei[N_EDGES + e];
    int pos = bnd[d] + rank[e];
    ssrc[pos] = ei[e];
    sea[pos] = edge_attr[e];
}

// ---------------- edge MLP via MFMA: 2 waves per node (R12 config) ----------------
__global__ void __launch_bounds__(256) edge_gather_mfma(
        const unsigned short* __restrict__ xh, const unsigned short* __restrict__ xl,
        const int* __restrict__ ssrc, const float* __restrict__ sea,
        const int* __restrict__ bnd,
        const unsigned short* __restrict__ w1fh, const unsigned short* __restrict__ w1fl,
        const unsigned short* __restrict__ w2fh, const unsigned short* __restrict__ w2fl,
        const float* __restrict__ w1, const float* __restrict__ b1,
        const float* __restrict__ b2,
        const float* __restrict__ lg, const float* __restrict__ lb,
        float* __restrict__ h) {
    __shared__ float Y[4][16 * 68];
    __shared__ float hpart[4][64];
    int lane = threadIdx.x & 63;
    int wv = threadIdx.x >> 6;
    int m = lane & 15;
    int q = lane >> 4;
    float* Yw = Y[wv];

    short8 b1h[4], b1l[4], b2h[8], b2l[8];
    #pragma unroll
    for (int g = 0; g < 4; g++) {
        b1h[g] = *(const short8*)(w1fh + (g * 64 + lane) * 8);
        b1l[g] = *(const short8*)(w1fl + (g * 64 + lane) * 8);
    }
    #pragma unroll
    for (int idx = 0; idx < 8; idx++) {
        b2h[idx] = *(const short8*)(w2fh + (idx * 64 + lane) * 8);
        b2l[idx] = *(const short8*)(w2fl + (idx * 64 + lane) * 8);
    }
    float w14[4], b1v[4], b2v[4], gam[4], bet[4];
    #pragma unroll
    for (int g = 0; g < 4; g++) {
        int row = g * 16 + m;
        w14[g] = w1[row * 15 + 14];
        b1v[g] = b1[row];
        b2v[g] = b2[row];
        gam[g] = lg[row];
        bet[g] = lb[row];
    }

    int node = blockIdx.x * 2 + (wv >> 1);
    int hf = wv & 1;
    int start = bnd[node], end = bnd[node + 1];
    int ntiles = (end - start + 15) >> 4;
    int h0 = (ntiles + 1) >> 1;
    int tcnt = hf ? (ntiles - h0) : h0;
    int astart = start + (hf ? h0 : 0) * 16;
    float acc[4] = {0.f, 0.f, 0.f, 0.f};

    for (int t = 0; t < tcnt; t++) {
        int base = astart + t * 16;
        int e = base + m;
        int srcn = ssrc[(e < end) ? e : (end - 1)];
        short8 a1h = (short8)0, a1l = (short8)0;
        if (q < 2) {
            a1h = *(const short8*)(xh + srcn * 16 + q * 8);
            a1l = *(const short8*)(xl + srcn * 16 + q * 8);
        }
        float ea[4];
        #pragma unroll
        for (int i = 0; i < 4; i++) {
            int idx = base + q * 4 + i;
            ea[i] = (idx < end) ? sea[idx] : 0.f;
        }
        f32x4 c1[4];
        #pragma unroll
        for (int g = 0; g < 4; g++) {
            f32x4 c = {0.f, 0.f, 0.f, 0.f};
            c = __builtin_amdgcn_mfma_f32_16x16x32_bf16(a1l, b1h[g], c, 0, 0, 0);
            c = __builtin_amdgcn_mfma_f32_16x16x32_bf16(a1h, b1l[g], c, 0, 0, 0);
            c = __builtin_amdgcn_mfma_f32_16x16x32_bf16(a1h, b1h[g], c, 0, 0, 0);
            c1[g] = c;
        }
        float s[4] = {0, 0, 0, 0}, s2[4] = {0, 0, 0, 0};
        float t1[4][4];
        #pragma unroll
        for (int g = 0; g < 4; g++) {
            #pragma unroll
            for (int i = 0; i < 4; i++) {
                float v = c1[g][i] + b1v[g] + w14[g] * ea[i];
                v = fmaxf(v, 0.f);
                t1[g][i] = v;
                s[i] += v;
                s2[i] += v * v;
            }
        }
        #pragma unroll
        for (int off = 1; off < 16; off <<= 1) {
            #pragma unroll
            for (int i = 0; i < 4; i++) {
                s[i] += __shfl_xor(s[i], off, 64);
                s2[i] += __shfl_xor(s2[i], off, 64);
            }
        }
        #pragma unroll
        for (int i = 0; i < 4; i++) {
            float mean = s[i] * (1.f / 64.f);
            float var = s2[i] * (1.f / 64.f) - mean * mean;
            s[i] = mean;
            s2[i] = rsqrtf(var + 1e-5f);
        }
        #pragma unroll
        for (int g = 0; g < 4; g++) {
            #pragma unroll
            for (int i = 0; i < 4; i++) {
                float y = (t1[g][i] - s[i]) * s2[i] * gam[g] + bet[g];
                Yw[(q * 4 + i) * 68 + g * 16 + m] = y;
            }
        }
        short8 a2h[2], a2l[2];
        #pragma unroll
        for (int t2 = 0; t2 < 2; t2++) {
            #pragma unroll
            for (int j = 0; j < 8; j++) {
                float v = Yw[m * 68 + t2 * 32 + q * 8 + j];
                short hi, lo;
                split_cheap(v, hi, lo);
                a2h[t2][j] = hi;
                a2l[t2][j] = lo;
            }
        }
        float s_[4] = {0, 0, 0, 0}, s2_[4] = {0, 0, 0, 0};
        float t2v[4][4];
        #pragma unroll
        for (int g = 0; g < 4; g++) {
            f32x4 c = {0.f, 0.f, 0.f, 0.f};
            #pragma unroll
            for (int t2 = 0; t2 < 2; t2++) {
                c = __builtin_amdgcn_mfma_f32_16x16x32_bf16(a2l[t2], b2h[g * 2 + t2], c, 0, 0, 0);
                c = __builtin_amdgcn_mfma_f32_16x16x32_bf16(a2h[t2], b2l[g * 2 + t2], c, 0, 0, 0);
                c = __builtin_amdgcn_mfma_f32_16x16x32_bf16(a2h[t2], b2h[g * 2 + t2], c, 0, 0, 0);
            }
            #pragma unroll
            for (int i = 0; i < 4; i++) {
                float v = c[i] + b2v[g];
                v = fmaxf(v, 0.f);
                t2v[g][i] = v;
                s_[i] += v;
                s2_[i] += v * v;
            }
        }
        #pragma unroll
        for (int off = 1; off < 16; off <<= 1) {
            #pragma unroll
            for (int i = 0; i < 4; i++) {
                s_[i] += __shfl_xor(s_[i], off, 64);
                s2_[i] += __shfl_xor(s2_[i], off, 64);
            }
        }
        #pragma unroll
        for (int i = 0; i < 4; i++) {
            float mean = s_[i] * (1.f / 64.f);
            float var = s2_[i] * (1.f / 64.f) - mean * mean;
            float rs = rsqrtf(var + 1e-5f);
            bool valid = (base + q * 4 + i) < end;
            #pragma unroll
            for (int g = 0; g < 4; g++) {
                float z = (t2v[g][i] - mean) * rs * gam[g] + bet[g];
                if (valid) acc[g] += z;
            }
        }
    }
    #pragma unroll
    for (int g = 0; g < 4; g++) {
        acc[g] += __shfl_xor(acc[g], 16, 64);
        acc[g] += __shfl_xor(acc[g], 32, 64);
    }
    float a01 = (q & 1) ? acc[1] : acc[0];
    float a23 = (q & 1) ? acc[3] : acc[2];
    float av = (q & 2) ? a23 : a01;
    hpart[wv][q * 16 + m] = av;
    __syncthreads();
    if (threadIdx.x < 128) {
        int nn = threadIdx.x >> 6, f = threadIdx.x & 63;
        h[(blockIdx.x * 2 + nn) * 64 + f] = hpart[2 * nn][f] + hpart[2 * nn + 1][f];
    }
}

// ------- qkv via MFMA (validated in mega P5): 3072 wave-tasks, 768 blocks -------
__global__ void __launch_bounds__(256) qkv_mfma(
        const float* __restrict__ h, const float* __restrict__ b,
        const unsigned short* __restrict__ ipfh, const unsigned short* __restrict__ ipfl,
        unsigned short* __restrict__ qhp, unsigned short* __restrict__ qlp,
        unsigned short* __restrict__ khp, unsigned short* __restrict__ klp,
        unsigned short* __restrict__ vT) {
    int lane = threadIdx.x & 63;
    int wv = threadIdx.x >> 6;
    int m = lane & 15;
    int q = lane >> 4;
    int wid = blockIdx.x * 4 + wv;   // 0..3071
    int tile = wid / 12;
    int og = wid - tile * 12;
    short8 bh[2], bl[2];
    #pragma unroll
    for (int t = 0; t < 2; t++) {
        bh[t] = *(const short8*)(ipfh + ((og * 2 + t) * 64 + lane) * 8);
        bl[t] = *(const short8*)(ipfl + ((og * 2 + t) * 64 + lane) * 8);
    }
    f32x4 c = {0.f, 0.f, 0.f, 0.f};
    #pragma unroll
    for (int t = 0; t < 2; t++) {
        const float* hr = h + (tile * 16 + m) * 64 + t * 32 + q * 8;
        float4 f0 = *(const float4*)hr;
        float4 f1 = *(const float4*)(hr + 4);
        float av8[8] = {f0.x, f0.y, f0.z, f0.w, f1.x, f1.y, f1.z, f1.w};
        short8 ah, al;
        #pragma unroll
        for (int j = 0; j < 8; j++) {
            short hi, lo;
            split_cheap(av8[j], hi, lo);
            ah[j] = hi;
            al[j] = lo;
        }
        c = __builtin_amdgcn_mfma_f32_16x16x32_bf16(al, bh[t], c, 0, 0, 0);
        c = __builtin_amdgcn_mfma_f32_16x16x32_bf16(ah, bl[t], c, 0, 0, 0);
        c = __builtin_amdgcn_mfma_f32_16x16x32_bf16(ah, bh[t], c, 0, 0, 0);
    }
    int o = og * 16 + m;
    float bias = b[o];
    #pragma unroll
    for (int r = 0; r < 4; r++) {
        int node = tile * 16 + q * 4 + r;   // C-layout row = (lane>>4)*4 + reg
        float val = c[r] + bias;
        if (og < 4) {
            float aq = val * (0.25f * 1.44269504f);   // fold 1/sqrt(16)*log2(e)
            size_t idx = ((size_t)(og * N_NODES + node)) * 16 + m;
            short hi = f2bf(aq);
            qhp[idx] = (unsigned short)hi;
            qlp[idx] = (unsigned short)f2bf(aq - bf2f(hi));
        } else if (og < 8) {
            size_t idx = ((size_t)((og - 4) * N_NODES + node)) * 16 + m;
            short hi = f2bf(val);
            khp[idx] = (unsigned short)hi;
            klp[idx] = (unsigned short)f2bf(val - bf2f(hi));
        } else {
            int feat = (og - 8) * 16 + m;
            vT[(size_t)feat * N_NODES + node] = (unsigned short)f2bf(val);
        }
    }
}

// ------- attention via MFMA: wave = (head, 16-q tile, 512-key chunk), 8192 tasks -------
__global__ void __launch_bounds__(256) attn_mfma(
        const unsigned short* __restrict__ qhp, const unsigned short* __restrict__ qlp,
        const unsigned short* __restrict__ khp, const unsigned short* __restrict__ klp,
        const unsigned short* __restrict__ vT,
        float* __restrict__ part_o, float* __restrict__ part_ml) {
    __shared__ unsigned short Pl[4][16 * 72];
    int lane = threadIdx.x & 63;
    int wv = threadIdx.x >> 6;
    int m = lane & 15;
    int g = lane >> 4;
    unsigned short* Pw = Pl[wv];
    const short8 vones = {0x3F80, 0x3F80, 0x3F80, 0x3F80, 0x3F80, 0x3F80, 0x3F80, 0x3F80};

    int wid = blockIdx.x * 4 + wv;     // 0..8191
    int kc = wid & 7;                  // 8 chunks of 512 keys
    int qt = (wid >> 3) & 255;
    int head = wid >> 11;

    short8 aqh = (short8)0, aql = (short8)0;
    if (g < 2) {
        size_t qi = ((size_t)(head * N_NODES + qt * 16 + m)) * 16 + g * 8;
        aqh = *(const short8*)(qhp + qi);
        aql = *(const short8*)(qlp + qi);
    }
    float mS[4], lS[4];
    #pragma unroll
    for (int r = 0; r < 4; r++) { mS[r] = -3e38f; lS[r] = 0.f; }
    f32x4 Ot = {0.f, 0.f, 0.f, 0.f};

    const unsigned short* khb = khp + (size_t)head * N_NODES * 16;
    const unsigned short* klb = klp + (size_t)head * N_NODES * 16;
    const unsigned short* vtb = vT + (size_t)(head * 16 + m) * N_NODES;

    for (int bblk = 0; bblk < 8; bblk++) {
        int n0 = kc * 512 + bblk * 64;
        f32x4 S[4];
        #pragma unroll
        for (int s = 0; s < 4; s++) {
            short8 bkh = (short8)0, bkl = (short8)0;
            if (g < 2) {
                size_t ki = ((size_t)(n0 + s * 16 + m)) * 16 + g * 8;
                bkh = *(const short8*)(khb + ki);
                bkl = *(const short8*)(klb + ki);
            }
            f32x4 c = {0.f, 0.f, 0.f, 0.f};
            c = __builtin_amdgcn_mfma_f32_16x16x32_bf16(aqh, bkl, c, 0, 0, 0);
            c = __builtin_amdgcn_mfma_f32_16x16x32_bf16(aql, bkh, c, 0, 0, 0);
            c = __builtin_amdgcn_mfma_f32_16x16x32_bf16(aqh, bkh, c, 0, 0, 0);
            S[s] = c;
        }
        float mr[4];
        #pragma unroll
        for (int r = 0; r < 4; r++)
            mr[r] = fmaxf(fmaxf(S[0][r], S[1][r]), fmaxf(S[2][r], S[3][r]));
        #pragma unroll
        for (int off = 1; off < 16; off <<= 1)
            #pragma unroll
            for (int r = 0; r < 4; r++) mr[r] = fmaxf(mr[r], __shfl_xor(mr[r], off, 64));
        float alpha[4];
        #pragma unroll
        for (int r = 0; r < 4; r++) {
            float mn = fmaxf(mS[r], mr[r]);
            alpha[r] = exp2f(mS[r] - mn);
            mS[r] = mn;
        }
        #pragma unroll
        for (int s = 0; s < 4; s++) {
            #pragma unroll
            for (int r = 0; r < 4; r++) {
                float p = exp2f(S[s][r] - mS[r]);
                Pw[(g * 4 + r) * 72 + s * 16 + m] = (unsigned short)f2bf(p);
            }
        }
        #pragma unroll
        for (int r = 0; r < 4; r++) lS[r] *= alpha[r];
        int sel = lane & 3;
        float a01 = (sel & 1) ? alpha[1] : alpha[0];
        float a23 = (sel & 1) ? alpha[3] : alpha[2];
        float aown = (sel & 2) ? a23 : a01;
        int srcl = ((m >> 2) << 4) | (m & 3);
        float ab = __int_as_float(__builtin_amdgcn_ds_bpermute(srcl << 2, __float_as_int(aown)));
        #pragma unroll
        for (int r = 0; r < 4; r++) Ot[r] *= ab;
        // PV + row-sums via ones-MFMA (cl[*] = rowsum[q=m]); bpermute to S-layout
        f32x4 cl = {0.f, 0.f, 0.f, 0.f};
        #pragma unroll
        for (int t = 0; t < 2; t++) {
            short8 avf = *(const short8*)(vtb + n0 + t * 32 + g * 8);
            short8 bpf = *(const short8*)(Pw + m * 72 + t * 32 + g * 8);
            cl = __builtin_amdgcn_mfma_f32_16x16x32_bf16(vones, bpf, cl, 0, 0, 0);
            Ot = __builtin_amdgcn_mfma_f32_16x16x32_bf16(avf, bpf, Ot, 0, 0, 0);
        }
        #pragma unroll
        for (int r = 0; r < 4; r++) {
            float rsum = __int_as_float(
                __builtin_amdgcn_ds_bpermute((g * 4 + r) << 2, __float_as_int(cl[0])));
            lS[r] += rsum;
        }
    }
    size_t pb = ((size_t)(head * 8 + kc) * 256 + qt) * 256;
    *(f32x4*)(part_o + pb + m * 16 + g * 4) = Ot;
    if (m == 0) {
        size_t mb = ((size_t)(head * 8 + kc) * 256 + qt) * 32;
        #pragma unroll
        for (int r = 0; r < 4; r++) {
            part_ml[mb + g * 4 + r] = mS[r];
            part_ml[mb + 16 + g * 4 + r] = lS[r];
        }
    }
}

// ---------------- fused merge (8 chunks) + out_proj + residual + LN + final ----------------
__global__ void post_kernel(const float* __restrict__ h,
                            const float* __restrict__ part_o, const float* __restrict__ part_ml,
                            const float* __restrict__ opw, const float* __restrict__ opb,
                            const float* __restrict__ ag, const float* __restrict__ ab,
                            const float* __restrict__ ow, const float* __restrict__ ob,
                            float* __restrict__ out) {
    __shared__ float wl1[64 * 65];
    __shared__ float wl2[64 * 65];
    for (int i = threadIdx.x; i < 4096; i += blockDim.x) {
        int r = i >> 6, c = i & 63;
        wl1[r * 65 + c] = opw[i];
        wl2[r * 65 + c] = ow[i];
    }
    __syncthreads();
    int lane = threadIdx.x & 63;
    int n = blockIdx.x * 4 + (threadIdx.x >> 6);
    int j = lane;
    int head = j >> 4, d = j & 15;
    int qt = n >> 4, qi = n & 15;
    float M = -3e38f, L = 0.f, Ov = 0.f;
    #pragma unroll
    for (int c = 0; c < 8; c++) {
        size_t base = ((size_t)(head * 8 + c) * 256 + qt);
        float mc = part_ml[base * 32 + qi];
        float lc = part_ml[base * 32 + 16 + qi];
        float ov = part_o[base * 256 + qi * 16 + d];
        if (mc > M) {
            float sc = exp2f(M - mc);
            M = mc;
            L = L * sc + lc;
            Ov = Ov * sc + ov;
        } else {
            float sc = exp2f(mc - M);
            L = fmaf(lc, sc, L);
            Ov = fmaf(ov, sc, Ov);
        }
    }
    float oj = Ov / L;
    float acc = opb[j];
    #pragma unroll
    for (int k = 0; k < 64; k++) acc = fmaf(wl1[j * 65 + k], bcastf(oj, k), acc);
    float r = h[n * 64 + j] + acc;
    float s = r, s2 = r * r;
    wave_sum2(s, s2);
    float mean = s * (1.f / 64.f);
    float var = s2 * (1.f / 64.f) - mean * mean;
    float hn = (r - mean) * rsqrtf(var + 1e-5f) * ag[j] + ab[j];
    float acc2 = ob[j];
    #pragma unroll
    for (int k = 0; k < 64; k++) acc2 = fmaf(wl2[j * 65 + k], bcastf(hn, k), acc2);
    out[n * 64 + j] = acc2;
}

extern "C" void kernel_launch(void* const* d_in, const int* in_sizes, int n_in,
                              void* d_out, int out_size, void* d_ws, size_t ws_size,
                              hipStream_t stream) {
    const float* x        = (const float*)d_in[0];
    const float* edge_attr= (const float*)d_in[1];
    const float* emb      = (const float*)d_in[2];
    const float* lin1_w   = (const float*)d_in[3];
    const float* lin1_b   = (const float*)d_in[4];
    const float* lay_w    = (const float*)d_in[5];
    const float* lay_b    = (const float*)d_in[6];
    const float* ln_g     = (const float*)d_in[7];
    const float* ln_b     = (const float*)d_in[8];
    const float* ipw      = (const float*)d_in[9];
    const float* ipb      = (const float*)d_in[10];
    const float* opw      = (const float*)d_in[11];
    const float* opb      = (const float*)d_in[12];
    const float* ang      = (const float*)d_in[13];
    const float* anb      = (const float*)d_in[14];
    const float* ow       = (const float*)d_in[15];
    const float* ob       = (const float*)d_in[16];
    const int*   ei       = (const int*)d_in[17];
    const int*   et       = (const int*)d_in[18];

    char* wsb = (char*)d_ws;
    size_t off = 0;
    unsigned short* xe_hi = (unsigned short*)(wsb + off); off += 131072;
    unsigned short* xe_lo = (unsigned short*)(wsb + off); off += 131072;
    float* h              = (float*)(wsb + off);          off += 1048576;
    unsigned short* qhp   = (unsigned short*)(wsb + off); off += 524288;
    unsigned short* qlp   = (unsigned short*)(wsb + off); off += 524288;
    unsigned short* khp   = (unsigned short*)(wsb + off); off += 524288;
    unsigned short* klp   = (unsigned short*)(wsb + off); off += 524288;
    unsigned short* vT    = (unsigned short*)(wsb + off); off += 524288;
    float* part_o         = (float*)(wsb + off);          off += 8388608;
    float* part_ml        = (float*)(wsb + off);          off += 1048576;
    int*   cnt            = (int*)(wsb + off);            off += 16384;
    int*   bnd            = (int*)(wsb + off);            off += 16388;
    off = (off + 255) & ~(size_t)255;
    int*   rank           = (int*)(wsb + off);            off += 2097152;
    int*   ssrc           = (int*)(wsb + off);            off += 2097152;
    float* sea            = (float*)(wsb + off);          off += 2097152;
    unsigned short* w1fh  = (unsigned short*)(wsb + off); off += 4096;
    unsigned short* w1fl  = (unsigned short*)(wsb + off); off += 4096;
    unsigned short* w2fh  = (unsigned short*)(wsb + off); off += 8192;
    unsigned short* w2fl  = (unsigned short*)(wsb + off); off += 8192;
    unsigned short* ipfh  = (unsigned short*)(wsb + off); off += 24576;
    unsigned short* ipfl  = (unsigned short*)(wsb + off); off += 24576;

    (void)hipMemsetAsync(cnt, 0, 4096 * sizeof(int), stream);
    xe_hist_wprep<<<2048, 256, 0, stream>>>(x, emb, et, ei, lin1_w, lay_w, ipw,
                                            xe_hi, xe_lo, cnt, rank,
                                            w1fh, w1fl, w2fh, w2fl, ipfh, ipfl);
    scan_kernel<<<1, 256, 0, stream>>>(cnt, bnd);
    scatter_kernel<<<2048, 256, 0, stream>>>(ei, edge_attr, bnd, rank, ssrc, sea);
    edge_gather_mfma<<<2048, 256, 0, stream>>>(xe_hi, xe_lo, ssrc, sea, bnd,
                                               w1fh, w1fl, w2fh, w2fl,
                                               lin1_w, lin1_b, lay_b, ln_g, ln_b, h);
    qkv_mfma<<<768, 256, 0, stream>>>(h, ipb, ipfh, ipfl, qhp, qlp, khp, klp, vT);
    attn_mfma<<<2048, 256, 0, stream>>>(qhp, qlp, khp, klp, vT, part_o, part_ml);
    post_kernel<<<1024, 256, 0, stream>>>(h, part_o, part_ml, opw, opb, ang, anb, ow, ob,
                                          (float*)d_out);
}

// Round 16
// 270.217 us; speedup vs baseline: 1.1191x; 1.0043x over previous
//
#include <hip/hip_runtime.h>

#define N_NODES 4096
#define N_EDGES 524288
#define HID 64

typedef short short8 __attribute__((ext_vector_type(8)));
typedef float f32x4 __attribute__((ext_vector_type(4)));

__device__ __forceinline__ float bcastf(float v, int l) {
    return __int_as_float(__builtin_amdgcn_readlane(__float_as_int(v), l));
}

__device__ __forceinline__ void wave_sum2(float& a, float& b) {
    #pragma unroll
    for (int off = 32; off > 0; off >>= 1) {
        a += __shfl_xor(a, off, 64);
        b += __shfl_xor(b, off, 64);
    }
}

__device__ __forceinline__ short f2bf(float f) {         // RNE
    unsigned u = __float_as_uint(f);
    u = u + 0x7FFFu + ((u >> 16) & 1u);
    return (short)(u >> 16);
}
__device__ __forceinline__ float bf2f(short s) {
    return __uint_as_float(((unsigned)(unsigned short)s) << 16);
}
__device__ __forceinline__ void split_cheap(float f, short& hi, short& lo) {
    unsigned u = __float_as_uint(f);
    unsigned hb = u & 0xffff0000u;
    float lof = f - __uint_as_float(hb);
    hi = (short)(u >> 16);
    lo = (short)(__float_as_uint(lof) >> 16);
}

// --- fused: xe hi/lo planes + dst histogram with rank + weight prepack (R14) ---
__global__ void xe_hist_wprep(const float* __restrict__ x, const float* __restrict__ emb,
                              const int* __restrict__ etype, const int* __restrict__ ei,
                              const float* __restrict__ w1, const float* __restrict__ w2,
                              const float* __restrict__ ipw,
                              unsigned short* __restrict__ xh, unsigned short* __restrict__ xl,
                              int* __restrict__ cnt, int* __restrict__ rank,
                              unsigned short* __restrict__ w1fh, unsigned short* __restrict__ w1fl,
                              unsigned short* __restrict__ w2fh, unsigned short* __restrict__ w2fl,
                              unsigned short* __restrict__ ipfh, unsigned short* __restrict__ ipfl) {
    int tid = blockIdx.x * 256 + threadIdx.x;    // grid exactly E
    int d = ei[N_EDGES + tid];
    rank[tid] = atomicAdd(&cnt[d], 1);
    if (tid < N_NODES * 16) {
        int n = tid >> 4, i = tid & 15;
        float v = 0.f;
        if (i < 6) v = x[n * 6 + i];
        else if (i < 14) v = emb[etype[n] * 8 + (i - 6)];
        short hi = f2bf(v);
        short lo = f2bf(v - bf2f(hi));
        xh[tid] = (unsigned short)hi;
        xl[tid] = (unsigned short)lo;
    }
    if (tid < 2048) {
        int g = tid >> 9, ln = (tid >> 3) & 63, j = tid & 7;
        int mm = ln & 15, qq = ln >> 4;
        int k = qq * 8 + j;
        float w = (k < 15) ? w1[(g * 16 + mm) * 15 + k] : 0.f;
        short hi = f2bf(w);
        w1fh[tid] = (unsigned short)hi;
        w1fl[tid] = (unsigned short)f2bf(w - bf2f(hi));
    }
    if (tid < 4096) {
        int idx = tid >> 9, ln = (tid >> 3) & 63, j = tid & 7;
        int mm = ln & 15, qq = ln >> 4;
        int g = idx >> 1, tt = idx & 1;
        float w = w2[(g * 16 + mm) * 64 + tt * 32 + qq * 8 + j];
        short hi = f2bf(w);
        w2fh[tid] = (unsigned short)hi;
        w2fl[tid] = (unsigned short)f2bf(w - bf2f(hi));
    }
    if (tid < 12288) {
        int idx = tid >> 9, ln = (tid >> 3) & 63, j = tid & 7;
        int mm = ln & 15, qq = ln >> 4;
        int og = idx >> 1, tt = idx & 1;
        float w = ipw[(og * 16 + mm) * 64 + tt * 32 + qq * 8 + j];
        short hi = f2bf(w);
        ipfh[tid] = (unsigned short)hi;
        ipfl[tid] = (unsigned short)f2bf(w - bf2f(hi));
    }
}

// ------- scatter with in-block scan (replaces scan_kernel + scatter_kernel) -------
// Each block recomputes the exclusive scan of cnt[4096] into LDS (cnt is L2-hot),
// then scatters its 256 edges. Block 0 also publishes bnd to global for edge kernel.
__global__ void __launch_bounds__(256) scatter_scan(
        const int* __restrict__ cnt, const int* __restrict__ ei,
        const float* __restrict__ edge_attr, const int* __restrict__ rank,
        int* __restrict__ bnd,
        int* __restrict__ ssrc, float* __restrict__ sea) {
    __shared__ int lbnd[4096];
    __shared__ int wsum[4];
    int t = threadIdx.x;
    int base = t * 16;
    int v16[16];
    int T = 0;
    #pragma unroll
    for (int j = 0; j < 16; j++) { v16[j] = cnt[base + j]; T += v16[j]; }
    int inc = T;
    int l = t & 63;
    #pragma unroll
    for (int off = 1; off < 64; off <<= 1) {
        int v = __shfl_up(inc, off, 64);
        if (l >= off) inc += v;
    }
    if (l == 63) wsum[t >> 6] = inc;
    __syncthreads();
    int wo = 0;
    for (int w = 0; w < (t >> 6); w++) wo += wsum[w];
    int run = wo + inc - T;
    #pragma unroll
    for (int j = 0; j < 16; j++) {
        lbnd[base + j] = run;
        run += v16[j];
    }
    if (blockIdx.x == 0) {
        #pragma unroll
        for (int j = 0; j < 16; j++) bnd[base + j] = lbnd[base + j];
        if (t == 255) bnd[4096] = run;
    }
    __syncthreads();
    int e = blockIdx.x * 256 + t;
    int d = ei[N_EDGES + e];
    int pos = lbnd[d] + rank[e];
    ssrc[pos] = ei[e];
    sea[pos] = edge_attr[e];
}

// ---------------- edge MLP via MFMA: 2 waves per node (R14 exact) ----------------
__global__ void __launch_bounds__(256) edge_gather_mfma(
        const unsigned short* __restrict__ xh, const unsigned short* __restrict__ xl,
        const int* __restrict__ ssrc, const float* __restrict__ sea,
        const int* __restrict__ bnd,
        const unsigned short* __restrict__ w1fh, const unsigned short* __restrict__ w1fl,
        const unsigned short* __restrict__ w2fh, const unsigned short* __restrict__ w2fl,
        const float* __restrict__ w1, const float* __restrict__ b1,
        const float* __restrict__ b2,
        const float* __restrict__ lg, const float* __restrict__ lb,
        float* __restrict__ h) {
    __shared__ float Y[4][16 * 68];
    __shared__ float hpart[4][64];
    int lane = threadIdx.x & 63;
    int wv = threadIdx.x >> 6;
    int m = lane & 15;
    int q = lane >> 4;
    float* Yw = Y[wv];

    short8 b1h[4], b1l[4], b2h[8], b2l[8];
    #pragma unroll
    for (int g = 0; g < 4; g++) {
        b1h[g] = *(const short8*)(w1fh + (g * 64 + lane) * 8);
        b1l[g] = *(const short8*)(w1fl + (g * 64 + lane) * 8);
    }
    #pragma unroll
    for (int idx = 0; idx < 8; idx++) {
        b2h[idx] = *(const short8*)(w2fh + (idx * 64 + lane) * 8);
        b2l[idx] = *(const short8*)(w2fl + (idx * 64 + lane) * 8);
    }
    float w14[4], b1v[4], b2v[4], gam[4], bet[4];
    #pragma unroll
    for (int g = 0; g < 4; g++) {
        int row = g * 16 + m;
        w14[g] = w1[row * 15 + 14];
        b1v[g] = b1[row];
        b2v[g] = b2[row];
        gam[g] = lg[row];
        bet[g] = lb[row];
    }

    int node = blockIdx.x * 2 + (wv >> 1);
    int hf = wv & 1;
    int start = bnd[node], end = bnd[node + 1];
    int ntiles = (end - start + 15) >> 4;
    int h0 = (ntiles + 1) >> 1;
    int tcnt = hf ? (ntiles - h0) : h0;
    int astart = start + (hf ? h0 : 0) * 16;
    float acc[4] = {0.f, 0.f, 0.f, 0.f};

    for (int t = 0; t < tcnt; t++) {
        int base = astart + t * 16;
        int e = base + m;
        int srcn = ssrc[(e < end) ? e : (end - 1)];
        short8 a1h = (short8)0, a1l = (short8)0;
        if (q < 2) {
            a1h = *(const short8*)(xh + srcn * 16 + q * 8);
            a1l = *(const short8*)(xl + srcn * 16 + q * 8);
        }
        float ea[4];
        #pragma unroll
        for (int i = 0; i < 4; i++) {
            int idx = base + q * 4 + i;
            ea[i] = (idx < end) ? sea[idx] : 0.f;
        }
        f32x4 c1[4];
        #pragma unroll
        for (int g = 0; g < 4; g++) {
            f32x4 c = {0.f, 0.f, 0.f, 0.f};
            c = __builtin_amdgcn_mfma_f32_16x16x32_bf16(a1l, b1h[g], c, 0, 0, 0);
            c = __builtin_amdgcn_mfma_f32_16x16x32_bf16(a1h, b1l[g], c, 0, 0, 0);
            c = __builtin_amdgcn_mfma_f32_16x16x32_bf16(a1h, b1h[g], c, 0, 0, 0);
            c1[g] = c;
        }
        float s[4] = {0, 0, 0, 0}, s2[4] = {0, 0, 0, 0};
        float t1[4][4];
        #pragma unroll
        for (int g = 0; g < 4; g++) {
            #pragma unroll
            for (int i = 0; i < 4; i++) {
                float v = c1[g][i] + b1v[g] + w14[g] * ea[i];
                v = fmaxf(v, 0.f);
                t1[g][i] = v;
                s[i] += v;
                s2[i] += v * v;
            }
        }
        #pragma unroll
        for (int off = 1; off < 16; off <<= 1) {
            #pragma unroll
            for (int i = 0; i < 4; i++) {
                s[i] += __shfl_xor(s[i], off, 64);
                s2[i] += __shfl_xor(s2[i], off, 64);
            }
        }
        #pragma unroll
        for (int i = 0; i < 4; i++) {
            float mean = s[i] * (1.f / 64.f);
            float var = s2[i] * (1.f / 64.f) - mean * mean;
            s[i] = mean;
            s2[i] = rsqrtf(var + 1e-5f);
        }
        #pragma unroll
        for (int g = 0; g < 4; g++) {
            #pragma unroll
            for (int i = 0; i < 4; i++) {
                float y = (t1[g][i] - s[i]) * s2[i] * gam[g] + bet[g];
                Yw[(q * 4 + i) * 68 + g * 16 + m] = y;
            }
        }
        short8 a2h[2], a2l[2];
        #pragma unroll
        for (int t2 = 0; t2 < 2; t2++) {
            #pragma unroll
            for (int j = 0; j < 8; j++) {
                float v = Yw[m * 68 + t2 * 32 + q * 8 + j];
                short hi, lo;
                split_cheap(v, hi, lo);
                a2h[t2][j] = hi;
                a2l[t2][j] = lo;
            }
        }
        float s_[4] = {0, 0, 0, 0}, s2_[4] = {0, 0, 0, 0};
        float t2v[4][4];
        #pragma unroll
        for (int g = 0; g < 4; g++) {
            f32x4 c = {0.f, 0.f, 0.f, 0.f};
            #pragma unroll
            for (int t2 = 0; t2 < 2; t2++) {
                c = __builtin_amdgcn_mfma_f32_16x16x32_bf16(a2l[t2], b2h[g * 2 + t2], c, 0, 0, 0);
                c = __builtin_amdgcn_mfma_f32_16x16x32_bf16(a2h[t2], b2l[g * 2 + t2], c, 0, 0, 0);
                c = __builtin_amdgcn_mfma_f32_16x16x32_bf16(a2h[t2], b2h[g * 2 + t2], c, 0, 0, 0);
            }
            #pragma unroll
            for (int i = 0; i < 4; i++) {
                float v = c[i] + b2v[g];
                v = fmaxf(v, 0.f);
                t2v[g][i] = v;
                s_[i] += v;
                s2_[i] += v * v;
            }
        }
        #pragma unroll
        for (int off = 1; off < 16; off <<= 1) {
            #pragma unroll
            for (int i = 0; i < 4; i++) {
                s_[i] += __shfl_xor(s_[i], off, 64);
                s2_[i] += __shfl_xor(s2_[i], off, 64);
            }
        }
        #pragma unroll
        for (int i = 0; i < 4; i++) {
            float mean = s_[i] * (1.f / 64.f);
            float var = s2_[i] * (1.f / 64.f) - mean * mean;
            float rs = rsqrtf(var + 1e-5f);
            bool valid = (base + q * 4 + i) < end;
            #pragma unroll
            for (int g = 0; g < 4; g++) {
                float z = (t2v[g][i] - mean) * rs * gam[g] + bet[g];
                if (valid) acc[g] += z;
            }
        }
    }
    #pragma unroll
    for (int g = 0; g < 4; g++) {
        acc[g] += __shfl_xor(acc[g], 16, 64);
        acc[g] += __shfl_xor(acc[g], 32, 64);
    }
    float a01 = (q & 1) ? acc[1] : acc[0];
    float a23 = (q & 1) ? acc[3] : acc[2];
    float av = (q & 2) ? a23 : a01;
    hpart[wv][q * 16 + m] = av;
    __syncthreads();
    if (threadIdx.x < 128) {
        int nn = threadIdx.x >> 6, f = threadIdx.x & 63;
        h[(blockIdx.x * 2 + nn) * 64 + f] = hpart[2 * nn][f] + hpart[2 * nn + 1][f];
    }
}

// ------- qkv via MFMA: 3072 wave-tasks, 768 blocks -------
__global__ void __launch_bounds__(256) qkv_mfma(
        const float* __restrict__ h, const float* __restrict__ b,
        const unsigned short* __restrict__ ipfh, const unsigned short* __restrict__ ipfl,
        unsigned short* __restrict__ qhp, unsigned short* __restrict__ qlp,
        unsigned short* __restrict__ khp, unsigned short* __restrict__ klp,
        unsigned short* __restrict__ vT) {
    int lane = threadIdx.x & 63;
    int wv = threadIdx.x >> 6;
    int m = lane & 15;
    int q = lane >> 4;
    int wid = blockIdx.x * 4 + wv;   // 0..3071
    int tile = wid / 12;
    int og = wid - tile * 12;
    short8 bh[2], bl[2];
    #pragma unroll
    for (int t = 0; t < 2; t++) {
        bh[t] = *(const short8*)(ipfh + ((og * 2 + t) * 64 + lane) * 8);
        bl[t] = *(const short8*)(ipfl + ((og * 2 + t) * 64 + lane) * 8);
    }
    f32x4 c = {0.f, 0.f, 0.f, 0.f};
    #pragma unroll
    for (int t = 0; t < 2; t++) {
        const float* hr = h + (tile * 16 + m) * 64 + t * 32 + q * 8;
        float4 f0 = *(const float4*)hr;
        float4 f1 = *(const float4*)(hr + 4);
        float av8[8] = {f0.x, f0.y, f0.z, f0.w, f1.x, f1.y, f1.z, f1.w};
        short8 ah, al;
        #pragma unroll
        for (int j = 0; j < 8; j++) {
            short hi, lo;
            split_cheap(av8[j], hi, lo);
            ah[j] = hi;
            al[j] = lo;
        }
        c = __builtin_amdgcn_mfma_f32_16x16x32_bf16(al, bh[t], c, 0, 0, 0);
        c = __builtin_amdgcn_mfma_f32_16x16x32_bf16(ah, bl[t], c, 0, 0, 0);
        c = __builtin_amdgcn_mfma_f32_16x16x32_bf16(ah, bh[t], c, 0, 0, 0);
    }
    int o = og * 16 + m;
    float bias = b[o];
    #pragma unroll
    for (int r = 0; r < 4; r++) {
        int node = tile * 16 + q * 4 + r;   // C-layout row = (lane>>4)*4 + reg
        float val = c[r] + bias;
        if (og < 4) {
            float aq = val * (0.25f * 1.44269504f);   // fold 1/sqrt(16)*log2(e)
            size_t idx = ((size_t)(og * N_NODES + node)) * 16 + m;
            short hi = f2bf(aq);
            qhp[idx] = (unsigned short)hi;
            qlp[idx] = (unsigned short)f2bf(aq - bf2f(hi));
        } else if (og < 8) {
            size_t idx = ((size_t)((og - 4) * N_NODES + node)) * 16 + m;
            short hi = f2bf(val);
            khp[idx] = (unsigned short)hi;
            klp[idx] = (unsigned short)f2bf(val - bf2f(hi));
        } else {
            int feat = (og - 8) * 16 + m;
            vT[(size_t)feat * N_NODES + node] = (unsigned short)f2bf(val);
        }
    }
}

// ------- attention via MFMA: wave = (head, 16-q tile, 512-key chunk), 8192 tasks -------
__global__ void __launch_bounds__(256) attn_mfma(
        const unsigned short* __restrict__ qhp, const unsigned short* __restrict__ qlp,
        const unsigned short* __restrict__ khp, const unsigned short* __restrict__ klp,
        const unsigned short* __restrict__ vT,
        float* __restrict__ part_o, float* __restrict__ part_ml) {
    __shared__ unsigned short Pl[4][16 * 72];
    int lane = threadIdx.x & 63;
    int wv = threadIdx.x >> 6;
    int m = lane & 15;
    int g = lane >> 4;
    unsigned short* Pw = Pl[wv];
    const short8 vones = {0x3F80, 0x3F80, 0x3F80, 0x3F80, 0x3F80, 0x3F80, 0x3F80, 0x3F80};

    int wid = blockIdx.x * 4 + wv;     // 0..8191
    int kc = wid & 7;                  // 8 chunks of 512 keys
    int qt = (wid >> 3) & 255;
    int head = wid >> 11;

    short8 aqh = (short8)0, aql = (short8)0;
    if (g < 2) {
        size_t qi = ((size_t)(head * N_NODES + qt * 16 + m)) * 16 + g * 8;
        aqh = *(const short8*)(qhp + qi);
        aql = *(const short8*)(qlp + qi);
    }
    float mS[4], lS[4];
    #pragma unroll
    for (int r = 0; r < 4; r++) { mS[r] = -3e38f; lS[r] = 0.f; }
    f32x4 Ot = {0.f, 0.f, 0.f, 0.f};

    const unsigned short* khb = khp + (size_t)head * N_NODES * 16;
    const unsigned short* klb = klp + (size_t)head * N_NODES * 16;
    const unsigned short* vtb = vT + (size_t)(head * 16 + m) * N_NODES;

    for (int bblk = 0; bblk < 8; bblk++) {
        int n0 = kc * 512 + bblk * 64;
        f32x4 S[4];
        #pragma unroll
        for (int s = 0; s < 4; s++) {
            short8 bkh = (short8)0, bkl = (short8)0;
            if (g < 2) {
                size_t ki = ((size_t)(n0 + s * 16 + m)) * 16 + g * 8;
                bkh = *(const short8*)(khb + ki);
                bkl = *(const short8*)(klb + ki);
            }
            f32x4 c = {0.f, 0.f, 0.f, 0.f};
            c = __builtin_amdgcn_mfma_f32_16x16x32_bf16(aqh, bkl, c, 0, 0, 0);
            c = __builtin_amdgcn_mfma_f32_16x16x32_bf16(aql, bkh, c, 0, 0, 0);
            c = __builtin_amdgcn_mfma_f32_16x16x32_bf16(aqh, bkh, c, 0, 0, 0);
            S[s] = c;
        }
        float mr[4];
        #pragma unroll
        for (int r = 0; r < 4; r++)
            mr[r] = fmaxf(fmaxf(S[0][r], S[1][r]), fmaxf(S[2][r], S[3][r]));
        #pragma unroll
        for (int off = 1; off < 16; off <<= 1)
            #pragma unroll
            for (int r = 0; r < 4; r++) mr[r] = fmaxf(mr[r], __shfl_xor(mr[r], off, 64));
        float alpha[4];
        #pragma unroll
        for (int r = 0; r < 4; r++) {
            float mn = fmaxf(mS[r], mr[r]);
            alpha[r] = exp2f(mS[r] - mn);
            mS[r] = mn;
        }
        #pragma unroll
        for (int s = 0; s < 4; s++) {
            #pragma unroll
            for (int r = 0; r < 4; r++) {
                float p = exp2f(S[s][r] - mS[r]);
                Pw[(g * 4 + r) * 72 + s * 16 + m] = (unsigned short)f2bf(p);
            }
        }
        #pragma unroll
        for (int r = 0; r < 4; r++) lS[r] *= alpha[r];
        int sel = lane & 3;
        float a01 = (sel & 1) ? alpha[1] : alpha[0];
        float a23 = (sel & 1) ? alpha[3] : alpha[2];
        float aown = (sel & 2) ? a23 : a01;
        int srcl = ((m >> 2) << 4) | (m & 3);
        float ab = __int_as_float(__builtin_amdgcn_ds_bpermute(srcl << 2, __float_as_int(aown)));
        #pragma unroll
        for (int r = 0; r < 4; r++) Ot[r] *= ab;
        // PV + row-sums via ones-MFMA (cl[*] = rowsum[q=m]); bpermute to S-layout
        f32x4 cl = {0.f, 0.f, 0.f, 0.f};
        #pragma unroll
        for (int t = 0; t < 2; t++) {
            short8 avf = *(const short8*)(vtb + n0 + t * 32 + g * 8);
            short8 bpf = *(const short8*)(Pw + m * 72 + t * 32 + g * 8);
            cl = __builtin_amdgcn_mfma_f32_16x16x32_bf16(vones, bpf, cl, 0, 0, 0);
            Ot = __builtin_amdgcn_mfma_f32_16x16x32_bf16(avf, bpf, Ot, 0, 0, 0);
        }
        #pragma unroll
        for (int r = 0; r < 4; r++) {
            float rsum = __int_as_float(
                __builtin_amdgcn_ds_bpermute((g * 4 + r) << 2, __float_as_int(cl[0])));
            lS[r] += rsum;
        }
    }
    size_t pb = ((size_t)(head * 8 + kc) * 256 + qt) * 256;
    *(f32x4*)(part_o + pb + m * 16 + g * 4) = Ot;
    if (m == 0) {
        size_t mb = ((size_t)(head * 8 + kc) * 256 + qt) * 32;
        #pragma unroll
        for (int r = 0; r < 4; r++) {
            part_ml[mb + g * 4 + r] = mS[r];
            part_ml[mb + 16 + g * 4 + r] = lS[r];
        }
    }
}

// ---------------- fused merge (8 chunks) + out_proj + residual + LN + final ----------------
__global__ void post_kernel(const float* __restrict__ h,
                            const float* __restrict__ part_o, const float* __restrict__ part_ml,
                            const float* __restrict__ opw, const float* __restrict__ opb,
                            const float* __restrict__ ag, const float* __restrict__ ab,
                            const float* __restrict__ ow, const float* __restrict__ ob,
                            float* __restrict__ out) {
    __shared__ float wl1[64 * 65];
    __shared__ float wl2[64 * 65];
    for (int i = threadIdx.x; i < 4096; i += blockDim.x) {
        int r = i >> 6, c = i & 63;
        wl1[r * 65 + c] = opw[i];
        wl2[r * 65 + c] = ow[i];
    }
    __syncthreads();
    int lane = threadIdx.x & 63;
    int n = blockIdx.x * 4 + (threadIdx.x >> 6);
    int j = lane;
    int head = j >> 4, d = j & 15;
    int qt = n >> 4, qi = n & 15;
    float M = -3e38f, L = 0.f, Ov = 0.f;
    #pragma unroll
    for (int c = 0; c < 8; c++) {
        size_t base = ((size_t)(head * 8 + c) * 256 + qt);
        float mc = part_ml[base * 32 + qi];
        float lc = part_ml[base * 32 + 16 + qi];
        float ov = part_o[base * 256 + qi * 16 + d];
        if (mc > M) {
            float sc = exp2f(M - mc);
            M = mc;
            L = L * sc + lc;
            Ov = Ov * sc + ov;
        } else {
            float sc = exp2f(mc - M);
            L = fmaf(lc, sc, L);
            Ov = fmaf(ov, sc, Ov);
        }
    }
    float oj = Ov / L;
    float acc = opb[j];
    #pragma unroll
    for (int k = 0; k < 64; k++) acc = fmaf(wl1[j * 65 + k], bcastf(oj, k), acc);
    float r = h[n * 64 + j] + acc;
    float s = r, s2 = r * r;
    wave_sum2(s, s2);
    float mean = s * (1.f / 64.f);
    float var = s2 * (1.f / 64.f) - mean * mean;
    float hn = (r - mean) * rsqrtf(var + 1e-5f) * ag[j] + ab[j];
    float acc2 = ob[j];
    #pragma unroll
    for (int k = 0; k < 64; k++) acc2 = fmaf(wl2[j * 65 + k], bcastf(hn, k), acc2);
    out[n * 64 + j] = acc2;
}

extern "C" void kernel_launch(void* const* d_in, const int* in_sizes, int n_in,
                              void* d_out, int out_size, void* d_ws, size_t ws_size,
                              hipStream_t stream) {
    const float* x        = (const float*)d_in[0];
    const float* edge_attr= (const float*)d_in[1];
    const float* emb      = (const float*)d_in[2];
    const float* lin1_w   = (const float*)d_in[3];
    const float* lin1_b   = (const float*)d_in[4];
    const float* lay_w    = (const float*)d_in[5];
    const float* lay_b    = (const float*)d_in[6];
    const float* ln_g     = (const float*)d_in[7];
    const float* ln_b     = (const float*)d_in[8];
    const float* ipw      = (const float*)d_in[9];
    const float* ipb      = (const float*)d_in[10];
    const float* opw      = (const float*)d_in[11];
    const float* opb      = (const float*)d_in[12];
    const float* ang      = (const float*)d_in[13];
    const float* anb      = (const float*)d_in[14];
    const float* ow       = (const float*)d_in[15];
    const float* ob       = (const float*)d_in[16];
    const int*   ei       = (const int*)d_in[17];
    const int*   et       = (const int*)d_in[18];

    char* wsb = (char*)d_ws;
    size_t off = 0;
    unsigned short* xe_hi = (unsigned short*)(wsb + off); off += 131072;
    unsigned short* xe_lo = (unsigned short*)(wsb + off); off += 131072;
    float* h              = (float*)(wsb + off);          off += 1048576;
    unsigned short* qhp   = (unsigned short*)(wsb + off); off += 524288;
    unsigned short* qlp   = (unsigned short*)(wsb + off); off += 524288;
    unsigned short* khp   = (unsigned short*)(wsb + off); off += 524288;
    unsigned short* klp   = (unsigned short*)(wsb + off); off += 524288;
    unsigned short* vT    = (unsigned short*)(wsb + off); off += 524288;
    float* part_o         = (float*)(wsb + off);          off += 8388608;
    float* part_ml        = (float*)(wsb + off);          off += 1048576;
    int*   cnt            = (int*)(wsb + off);            off += 16384;
    int*   bnd            = (int*)(wsb + off);            off += 16388;
    off = (off + 255) & ~(size_t)255;
    int*   rank           = (int*)(wsb + off);            off += 2097152;
    int*   ssrc           = (int*)(wsb + off);            off += 2097152;
    float* sea            = (float*)(wsb + off);          off += 2097152;
    unsigned short* w1fh  = (unsigned short*)(wsb + off); off += 4096;
    unsigned short* w1fl  = (unsigned short*)(wsb + off); off += 4096;
    unsigned short* w2fh  = (unsigned short*)(wsb + off); off += 8192;
    unsigned short* w2fl  = (unsigned short*)(wsb + off); off += 8192;
    unsigned short* ipfh  = (unsigned short*)(wsb + off); off += 24576;
    unsigned short* ipfl  = (unsigned short*)(wsb + off); off += 24576;

    (void)hipMemsetAsync(cnt, 0, 4096 * sizeof(int), stream);
    xe_hist_wprep<<<2048, 256, 0, stream>>>(x, emb, et, ei, lin1_w, lay_w, ipw,
                                            xe_hi, xe_lo, cnt, rank,
                                            w1fh, w1fl, w2fh, w2fl, ipfh, ipfl);
    scatter_scan<<<2048, 256, 0, stream>>>(cnt, ei, edge_attr, rank, bnd, ssrc, sea);
    edge_gather_mfma<<<2048, 256, 0, stream>>>(xe_hi, xe_lo, ssrc, sea, bnd,
                                               w1fh, w1fl, w2fh, w2fl,
                                               lin1_w, lin1_b, lay_b, ln_g, ln_b, h);
    qkv_mfma<<<768, 256, 0, stream>>>(h, ipb, ipfh, ipfl, qhp, qlp, khp, klp, vT);
    attn_mfma<<<2048, 256, 0, stream>>>(qhp, qlp, khp, klp, vT, part_o, part_ml);
    post_kernel<<<1024, 256, 0, stream>>>(h, part_o, part_ml, opw, opb, ang, anb, ow, ob,
                                          (float*)d_out);
}